// Round 10
// baseline (137.870 us; speedup 1.0000x reference)
//
#include <hip/hip_runtime.h>

#define TPB 256
#define EPB 8             // elements per block; wave owns 2 (half-wave each in P1-P4)
#define H1S 246           // padded row stride for h1 (245 used; holds 140-vec later)
#define ES  280           // per-element slot: x(256) then h[140]|t30[60]

// ---- d_ws float offsets ----
#define WQ1   0      // 65
#define WQ2   65     // 450
#define WR1Q  515    // 100
#define WR2Q  615    // 100
#define WCQ   715    // 64 (c1 @715, c2 @747)
#define WSB   779    // 474 folded BN
#define SMALL_N 1253
// A-weights, blocked-transposed: [35 float4-col-blocks][140 fused rows] float4
#define WQAT  1280   // 19600
// B-weights, blocked-transposed: [35 float2-col-blocks][60 fused rows] float2
#define WQBT  20880  // 4200

// sb sub-offsets (relative to WSB): [scale[C] | bias[C]] per layer
#define SB_P1 0
#define SB_P2 10
#define SB_R1 30
#define SB_R2 50
#define SB_A1 70
#define SB_B1 210
#define SB_C1 270
#define SB_A2 272
#define SB_B2 412
#define SB_C2 472

// ---------------- prep: quantize weights + fold BN into ws ----------------
#define GFOLD(bn, C, OFF)                                                     \
  if (tid < (C)) {                                                            \
    float gg = (bn)[tid], bb = (bn)[(C) + tid];                               \
    float mm = (bn)[2 * (C) + tid], vv = (bn)[3 * (C) + tid];                 \
    float sc = gg / sqrtf(vv + 1e-5f);                                        \
    sbp[(OFF) + tid] = sc;                                                    \
    sbp[(OFF) + (C) + tid] = bb - mm * sc;                                    \
  }

extern "C" __global__ __launch_bounds__(256)
void prep(const float* __restrict__ w1,  const float* __restrict__ bnp1,
          const float* __restrict__ w2,  const float* __restrict__ bnp2,
          const float* __restrict__ wr1, const float* __restrict__ bnr1,
          const float* __restrict__ wr2, const float* __restrict__ bnr2,
          const float* __restrict__ wa1, const float* __restrict__ bna1,
          const float* __restrict__ wb1, const float* __restrict__ bnb1,
          const float* __restrict__ wc1, const float* __restrict__ bnc1,
          const float* __restrict__ wa2, const float* __restrict__ bna2,
          const float* __restrict__ wb2, const float* __restrict__ bnb2,
          const float* __restrict__ wc2, const float* __restrict__ bnc2,
          float* __restrict__ ws)
{
  __shared__ float s_red[4];
  const int tid = threadIdx.x;
  const int b = blockIdx.x;

  if (b == 10) {  // fold all BN params
    float* sbp = ws + WSB;
    GFOLD(bnp1, 5, SB_P1)  GFOLD(bnp2, 10, SB_P2)
    GFOLD(bnr1, 10, SB_R1) GFOLD(bnr2, 10, SB_R2)
    GFOLD(bna1, 70, SB_A1) GFOLD(bnb1, 30, SB_B1) GFOLD(bnc1, 1, SB_C1)
    GFOLD(bna2, 70, SB_A2) GFOLD(bnb2, 30, SB_B2) GFOLD(bnc2, 1, SB_C2)
    return;
  }

  const float* src; int n; int mode; int rofs; float* dst = ws;
  int ofs = 0;
  switch (b) {
    case 0: src = w1;  ofs = WQ1;      n = 65;   mode = 0; rofs = 0;  break;
    case 1: src = w2;  ofs = WQ2;      n = 450;  mode = 0; rofs = 0;  break;
    case 2: src = wr1; ofs = WR1Q;     n = 100;  mode = 0; rofs = 0;  break;
    case 3: src = wr2; ofs = WR2Q;     n = 100;  mode = 0; rofs = 0;  break;
    case 4: src = wa1; ofs = WQAT;     n = 9800; mode = 1; rofs = 0;  break;
    case 5: src = wb1; ofs = WQBT;     n = 2100; mode = 2; rofs = 0;  break;
    case 6: src = wc1; ofs = WCQ;      n = 30;   mode = 0; rofs = 0;  break;
    case 7: src = wa2; ofs = WQAT;     n = 9800; mode = 1; rofs = 70; break;
    case 8: src = wb2; ofs = WQBT;     n = 2100; mode = 2; rofs = 30; break;
    default:src = wc2; ofs = WCQ + 32; n = 30;   mode = 0; rofs = 0;  break;
  }

  const int n4 = n >> 2;
  const float4* s4 = (const float4*)src;

  float m = 0.f;
  for (int i = tid; i < n4; i += 256) {
    float4 v = s4[i];
    m = fmaxf(m, fmaxf(fmaxf(fabsf(v.x), fabsf(v.y)),
                       fmaxf(fabsf(v.z), fabsf(v.w))));
  }
  for (int i = (n4 << 2) + tid; i < n; i += 256) m = fmaxf(m, fabsf(src[i]));
#pragma unroll
  for (int off = 32; off > 0; off >>= 1)
    m = fmaxf(m, __shfl_down(m, off, 64));
  if ((tid & 63) == 0) s_red[tid >> 6] = m;
  __syncthreads();
  m = fmaxf(fmaxf(s_red[0], s_red[1]), fmaxf(s_red[2], s_red[3]));

  const float s = m / 127.0f;
  auto qz = [&](float w) {
    return rintf(fminf(fmaxf(w / s, -127.f), 127.f)) * s;
  };

  if (mode == 0) {
    for (int i = tid; i < n4; i += 256) {
      float4 v = s4[i];
      int base = 4 * i;
      dst[ofs + base]     = qz(v.x);
      dst[ofs + base + 1] = qz(v.y);
      dst[ofs + base + 2] = qz(v.z);
      dst[ofs + base + 3] = qz(v.w);
    }
    for (int i = (n4 << 2) + tid; i < n; i += 256) dst[ofs + i] = qz(src[i]);
  } else if (mode == 1) {           // A: row r, col c -> [c/4][r] float4
    // 140 % 4 == 0 => a float4 load never crosses a row; c % 4 == 0
    for (int i = tid; i < n4; i += 256) {
      float4 v = s4[i];
      int base = 4 * i;
      int r = base / 140 + rofs, c = base % 140;
      float4 q4;
      q4.x = qz(v.x); q4.y = qz(v.y); q4.z = qz(v.z); q4.w = qz(v.w);
      *(float4*)&dst[ofs + ((c >> 2) * 140 + r) * 4] = q4;
    }
  } else {                          // B: row r, col c -> [c/2][r] float2
    // rows of 70 can be crossed mid-float4; recompute (r,c) per component
    for (int i = tid; i < n4; i += 256) {
      float4 v = s4[i];
      int base = 4 * i;
      float q[4] = {qz(v.x), qz(v.y), qz(v.z), qz(v.w)};
#pragma unroll
      for (int cpt = 0; cpt < 4; ++cpt) {
        int ii = base + cpt;
        int r = ii / 70 + rofs, c = ii % 70;
        dst[ofs + ((c >> 1) * 60 + r) * 2 + (c & 1)] = q[cpt];
      }
    }
  }
}

// -------- main pipeline: wave owns 2 elements, ZERO barriers --------------
// R20 = R18 (131.4 best) + ONE knob: A-loop unroll 2 -> 5. Rationale:
// A-weights (78.4KB) miss L1 -> every weight load is an L2 hit (~200cy);
// unroll 2 keeps only ~4 VMEM in flight. We are GRID-capped at 4 waves/SIMD,
// so VGPR up to 128 is free (launch_bounds(256,4)); spend it on MLP: unroll 5
// puts ~15 independent loads in flight, hiding L2 latency under the VALU
// burst. R19's VMEM-weight move was neutral -> DS/VMEM placement not binding;
// latency is the remaining candidate.
extern "C" __global__ __launch_bounds__(TPB, 4)
void taunet(const float* __restrict__ x, const float* __restrict__ ws,
            float* __restrict__ out, int B)
{
  __shared__ __align__(16) float s_h1[EPB * H1S];   // pre1 out; later 140-vec
  __shared__ __align__(16) float s_e[EPB * ES];     // x -> h[140]|t30[60]
  __shared__ __align__(16) float s_small[SMALL_N];

  const int tid = threadIdx.x;
  const int g  = tid >> 5;    // element slot within block (half-wave)
  const int l  = tid & 31;    // lane within element (P1-P4, C)
  const int ln = tid & 63;    // lane within wave
  const int wv = tid >> 6;    // wave within block
  const int gp = 2 * wv;      // wave's first element slot
  const int elem = blockIdx.x * EPB + g;

  // per-wave redundant copy of small weights+BN (identical values -> benign
  // race; each wave's own writes are ordered before its reads => no barrier)
  {
    const float4* w4p = (const float4*)ws;
    for (int i = ln; i < (SMALL_N >> 2); i += 64)   // 313 float4 = 1252 floats
      *(float4*)&s_small[i * 4] = w4p[i];
    if (ln == 0) s_small[1252] = ws[1252];
  }

  // stage x: wave stages its own two elements (coalesced float4)
  {
    const float4* xb = (const float4*)x;
#pragma unroll
    for (int it = 0; it < 2; ++it) {
      int e = gp + it;
      int ge = blockIdx.x * EPB + e;
      if (ge < B) {
        float4 v = xb[ge * 64 + ln];
        *(float4*)&s_e[e * ES + ln * 4] = v;
      }
    }
  }

  const float* sb = &s_small[WSB];

  // ---- P1: pre1 (Cin=1, K=13, stride 5) -> h1[5][49] ----
  // weights + BN wave-uniform from ws[] -> scalar s_loads (SMEM pipe)
  {
    const float* xe = &s_e[g * ES];
#pragma unroll
    for (int rep = 0; rep < 2; ++rep) {
      int p = l + 32 * rep;
      bool act = p < 49;
      int ps = act ? p : 0;
      float win[13];
#pragma unroll
      for (int k = 0; k < 13; ++k) win[k] = xe[5 * ps + k];
#pragma unroll
      for (int ci = 0; ci < 5; ++ci) {
        float a0 = 0.f, a1 = 0.f;
#pragma unroll
        for (int k = 0; k < 13; ++k) {
          float d = fabsf(win[k] - ws[WQ1 + ci * 13 + k]);
          if (k & 1) a1 += d; else a0 += d;
        }
        float v = fmaxf(fmaf(-(a0 + a1), ws[WSB + SB_P1 + ci],
                             ws[WSB + SB_P1 + 5 + ci]), 0.f);
        if (act) s_h1[g * H1S + ci * 49 + ps] = v;
      }
    }
  }

  // ---- P2: pre2 (Cin=5, K=9, stride 3) -> h2[10][14] ----
  // half-wave: lane = ow(14 of 16) x co-half(2); ci-outer, 9-reg window
  {
    const int ch = l >> 4;
    const int ow16 = l & 15;
    const bool act = ow16 < 14;
    const int ow = act ? ow16 : 0;
    const float* h1b = &s_h1[g * H1S];
    float acc[5] = {0.f, 0.f, 0.f, 0.f, 0.f};
#pragma unroll
    for (int ci = 0; ci < 5; ++ci) {
      float w9[9];
#pragma unroll
      for (int k = 0; k < 9; ++k) w9[k] = h1b[ci * 49 + 3 * ow + k];
#pragma unroll
      for (int c = 0; c < 5; ++c) {
        int co = ch * 5 + c;
        float s0 = 0.f, s1 = 0.f;
#pragma unroll
        for (int k = 0; k < 9; ++k) {
          float d = fabsf(w9[k] - s_small[WQ2 + co * 45 + ci * 9 + k]);
          if (k & 1) s1 += d; else s0 += d;
        }
        acc[c] += s0 + s1;
      }
    }
#pragma unroll
    for (int c = 0; c < 5; ++c) {
      int co = ch * 5 + c;
      float v = fmaxf(fmaf(-acc[c], sb[SB_P2 + co], sb[SB_P2 + 10 + co]), 0.f);
      if (act) s_e[g * ES + co * 14 + ow] = v;
    }
  }

  // ---- P3: r1 (10x10, K=1) + relu -> t1 ----
#pragma unroll
  for (int j = 0; j < 5; ++j) {
    int idx = l + 32 * j;
    if (idx < 140) {
      int co = idx / 14, ow = idx % 14;
      float a0 = 0.f, a1 = 0.f;
#pragma unroll
      for (int ci = 0; ci < 10; ++ci) {
        float d = fabsf(s_e[g * ES + ci * 14 + ow] - s_small[WR1Q + co * 10 + ci]);
        if (ci & 1) a1 += d; else a0 += d;
      }
      s_e[g * ES + 140 + idx] =
          fmaxf(fmaf(-(a0 + a1), sb[SB_R1 + co], sb[SB_R1 + 10 + co]), 0.f);
    }
  }

  // ---- P4: r2 (no relu) + residual, h = relu(t2 + h2), in place ----
#pragma unroll
  for (int j = 0; j < 5; ++j) {
    int idx = l + 32 * j;
    if (idx < 140) {
      int co = idx / 14, ow = idx % 14;
      float a0 = 0.f, a1 = 0.f;
#pragma unroll
      for (int ci = 0; ci < 10; ++ci) {
        float d = fabsf(s_e[g * ES + 140 + ci * 14 + ow] - s_small[WR2Q + co * 10 + ci]);
        if (ci & 1) a1 += d; else a0 += d;
      }
      float t2 = fmaf(-(a0 + a1), sb[SB_R2 + co], sb[SB_R2 + 10 + co]);
      s_e[g * ES + idx] = fmaxf(t2 + s_e[g * ES + idx], 0.f);
    }
  }

  // ---- A/B fused branches, wave-wide ----
  {
    const float* hb0 = &s_e[gp * ES];         // element e0 = gp
    const float* hb1 = &s_e[(gp + 1) * ES];   // element e1 = gp+1

    // A: cb-outer; h4/k4 LDS-read ONCE per cb. Sets 0,1: rows ln / ln+64 for
    // BOTH elements (dual accumulators). Set 2 packed: rows 128-139 of elem0
    // on lanes 0-11, of elem1 on lanes 12-23 -> single-elem cost. p4 comes
    // from REGISTERS (cndmask h4/k4), not a 3rd LDS read (R18). R20: unroll 5
    // (35 = 5x7) for ~15 loads in flight -> hide L2 latency (A-weights
    // 78.4KB do not fit 32KB L1).
    const int r01[2] = {ln, ln + 64};
    const bool s2a = ln < 12;
    const bool s2b = (ln >= 12) && (ln < 24);
    const int r2 = 128 + (s2a ? ln : (s2b ? ln - 12 : 0));

    float accA[2][4], accB[2][4], acc2[4];
#pragma unroll
    for (int p = 0; p < 2; ++p)
#pragma unroll
      for (int j = 0; j < 4; ++j) { accA[p][j] = 0.f; accB[p][j] = 0.f; }
#pragma unroll
    for (int j = 0; j < 4; ++j) acc2[j] = 0.f;

#pragma unroll 5
    for (int cb = 0; cb < 35; ++cb) {
      float4 h4 = *(const float4*)&hb0[cb * 4];
      float4 k4 = *(const float4*)&hb1[cb * 4];
      float4 p4;                     // duplicate of h4 (lanes<12) / k4 (12..23)
      p4.x = s2a ? h4.x : k4.x;
      p4.y = s2a ? h4.y : k4.y;
      p4.z = s2a ? h4.z : k4.z;
      p4.w = s2a ? h4.w : k4.w;
#pragma unroll
      for (int p = 0; p < 2; ++p) {
        float4 w4 = *(const float4*)&ws[WQAT + (cb * 140 + r01[p]) * 4];
        accA[p][0] += fabsf(h4.x - w4.x);
        accA[p][1] += fabsf(h4.y - w4.y);
        accA[p][2] += fabsf(h4.z - w4.z);
        accA[p][3] += fabsf(h4.w - w4.w);
        accB[p][0] += fabsf(k4.x - w4.x);
        accB[p][1] += fabsf(k4.y - w4.y);
        accB[p][2] += fabsf(k4.z - w4.z);
        accB[p][3] += fabsf(k4.w - w4.w);
      }
      float4 w2v = *(const float4*)&ws[WQAT + (cb * 140 + r2) * 4];
      acc2[0] += fabsf(p4.x - w2v.x);
      acc2[1] += fabsf(p4.y - w2v.y);
      acc2[2] += fabsf(p4.z - w2v.z);
      acc2[3] += fabsf(p4.w - w2v.w);
    }
#pragma unroll
    for (int p = 0; p < 2; ++p) {
      int cl = r01[p];
      int co  = cl < 70 ? cl : cl - 70;
      int off = cl < 70 ? SB_A1 : SB_A2;
      float sc = sb[off + co], bi = sb[off + 70 + co];
      float sadA = (accA[p][0] + accA[p][1]) + (accA[p][2] + accA[p][3]);
      float sadB = (accB[p][0] + accB[p][1]) + (accB[p][2] + accB[p][3]);
      s_h1[gp * H1S + cl]       = fmaxf(fmaf(-sadA, sc, bi), 0.f);
      s_h1[(gp + 1) * H1S + cl] = fmaxf(fmaf(-sadB, sc, bi), 0.f);
    }
    if (s2a || s2b) {
      int cl = r2;                         // 128..139 -> always branch 2
      int co = cl - 70;
      float sc = sb[SB_A2 + co], bi = sb[SB_A2 + 70 + co];
      float sad = (acc2[0] + acc2[1]) + (acc2[2] + acc2[3]);
      int e = s2a ? gp : (gp + 1);
      s_h1[e * H1S + cl] = fmaxf(fmaf(-sad, sc, bi), 0.f);
    }

    // B: 60 fused rows in one pass; dense float2 weight loads + float2 h reads
    {
      bool act = ln < 60;
      int rl = act ? ln : 0;
      int br = rl >= 30;
      int co = br ? rl - 30 : rl;
      const float* h0 = &s_h1[gp * H1S + br * 70];
      const float* h1 = &s_h1[(gp + 1) * H1S + br * 70];
      int off = br ? SB_B2 : SB_B1;
      float a0 = 0.f, a1 = 0.f, b0 = 0.f, b1 = 0.f;
#pragma unroll 8
      for (int ci = 0; ci < 35; ++ci) {
        float2 w2v = *(const float2*)&ws[WQBT + (ci * 60 + rl) * 2];
        float2 hv0 = *(const float2*)&h0[2 * ci];
        float2 hv1 = *(const float2*)&h1[2 * ci];
        a0 += fabsf(hv0.x - w2v.x);
        a1 += fabsf(hv0.y - w2v.y);
        b0 += fabsf(hv1.x - w2v.x);
        b1 += fabsf(hv1.y - w2v.y);
      }
      if (act) {
        float sc = sb[off + co], bi = sb[off + 30 + co];
        s_e[gp * ES + 140 + rl]       = fmaxf(fmaf(-(a0 + a1), sc, bi), 0.f);
        s_e[(gp + 1) * ES + 140 + rl] = fmaxf(fmaf(-(b0 + b1), sc, bi), 0.f);
      }
    }

    // C: per element (half-wave), both branches sequentially; width-32 tree
    for (int br = 0; br < 2; ++br) {
      float d = 0.f;
      if (l < 30)
        d = fabsf(s_e[g * ES + 140 + br * 30 + l] - s_small[WCQ + br * 32 + l]);
#pragma unroll
      for (int off = 16; off > 0; off >>= 1)
        d += __shfl_down(d, off, 32);
      if (l == 0 && elem < B) {
        int sbC = br ? SB_C2 : SB_C1;
        out[br * B + elem] = fmaxf(fmaf(-d, sb[sbC], sb[sbC + 1]), 0.f);
      }
    }
  }
}

extern "C" void kernel_launch(void* const* d_in, const int* in_sizes, int n_in,
                              void* d_out, int out_size, void* d_ws, size_t ws_size,
                              hipStream_t stream) {
  const float* x    = (const float*)d_in[0];
  const float* w1   = (const float*)d_in[1];
  const float* bnp1 = (const float*)d_in[2];
  const float* w2   = (const float*)d_in[3];
  const float* bnp2 = (const float*)d_in[4];
  const float* wr1  = (const float*)d_in[5];
  const float* bnr1 = (const float*)d_in[6];
  const float* wr2  = (const float*)d_in[7];
  const float* bnr2 = (const float*)d_in[8];
  const float* wa1  = (const float*)d_in[9];
  const float* bna1 = (const float*)d_in[10];
  const float* wb1  = (const float*)d_in[11];
  const float* bnb1 = (const float*)d_in[12];
  const float* wc1  = (const float*)d_in[13];
  const float* bnc1 = (const float*)d_in[14];
  const float* wa2  = (const float*)d_in[15];
  const float* bna2 = (const float*)d_in[16];
  const float* wb2  = (const float*)d_in[17];
  const float* bnb2 = (const float*)d_in[18];
  const float* wc2  = (const float*)d_in[19];
  const float* bnc2 = (const float*)d_in[20];

  float* ws = (float*)d_ws;
  int B = in_sizes[0] / 256;
  int blocks = (B + EPB - 1) / EPB;

  hipLaunchKernelGGL(prep, dim3(11), dim3(256), 0, stream,
                     w1, bnp1, w2, bnp2, wr1, bnr1, wr2, bnr2,
                     wa1, bna1, wb1, bnb1, wc1, bnc1,
                     wa2, bna2, wb2, bnb2, wc2, bnc2, ws);

  hipLaunchKernelGGL(taunet, dim3(blocks), dim3(TPB), 0, stream,
                     x, ws, (float*)d_out, B);
}

// Round 11
// 128.067 us; speedup vs baseline: 1.0766x; 1.0766x over previous
//
#include <hip/hip_runtime.h>

#define TPB 256
#define EPB 8             // elements per block; wave owns 2 (half-wave each in P1-P4)
#define H1S 246           // padded row stride for h1 (245 used; holds 140-vec later)
#define ES  280           // per-element slot: x(256) then h[140]|t30[60]

// ---- d_ws float offsets ----
#define WQ1   0      // 65
#define WQ2   65     // 450
#define WR1Q  515    // 100
#define WR2Q  615    // 100
#define WCQ   715    // 64 (c1 @715, c2 @747)
#define WSB   779    // 474 folded BN
#define SMALL_N 1253
// A-weights, blocked-transposed: [35 float4-col-blocks][140 fused rows] float4
#define WQAT  1280   // 19600
// B-weights, blocked-transposed: [35 float2-col-blocks][60 fused rows] float2
#define WQBT  20880  // 4200

// sb sub-offsets (relative to WSB): [scale[C] | bias[C]] per layer
#define SB_P1 0
#define SB_P2 10
#define SB_R1 30
#define SB_R2 50
#define SB_A1 70
#define SB_B1 210
#define SB_C1 270
#define SB_A2 272
#define SB_B2 412
#define SB_C2 472

// ---------------- prep: quantize weights + fold BN into ws ----------------
// R21: the two 9800-elem mode-1 blocks are split 4 ways (blocks 4,11-13 =
// wa1 parts 0-3; blocks 7,14-16 = wa2 parts 0-3). Each part redundantly
// computes the cheap absmax over all 9800 (10 vec iters), then quantizes
// only its quarter -> store phase 4x parallel. Values and write-once
// semantics unchanged.
#define GFOLD(bn, C, OFF)                                                     \
  if (tid < (C)) {                                                            \
    float gg = (bn)[tid], bb = (bn)[(C) + tid];                               \
    float mm = (bn)[2 * (C) + tid], vv = (bn)[3 * (C) + tid];                 \
    float sc = gg / sqrtf(vv + 1e-5f);                                        \
    sbp[(OFF) + tid] = sc;                                                    \
    sbp[(OFF) + (C) + tid] = bb - mm * sc;                                    \
  }

extern "C" __global__ __launch_bounds__(256)
void prep(const float* __restrict__ w1,  const float* __restrict__ bnp1,
          const float* __restrict__ w2,  const float* __restrict__ bnp2,
          const float* __restrict__ wr1, const float* __restrict__ bnr1,
          const float* __restrict__ wr2, const float* __restrict__ bnr2,
          const float* __restrict__ wa1, const float* __restrict__ bna1,
          const float* __restrict__ wb1, const float* __restrict__ bnb1,
          const float* __restrict__ wc1, const float* __restrict__ bnc1,
          const float* __restrict__ wa2, const float* __restrict__ bna2,
          const float* __restrict__ wb2, const float* __restrict__ bnb2,
          const float* __restrict__ wc2, const float* __restrict__ bnc2,
          float* __restrict__ ws)
{
  __shared__ float s_red[4];
  const int tid = threadIdx.x;
  const int b = blockIdx.x;

  if (b == 10) {  // fold all BN params
    float* sbp = ws + WSB;
    GFOLD(bnp1, 5, SB_P1)  GFOLD(bnp2, 10, SB_P2)
    GFOLD(bnr1, 10, SB_R1) GFOLD(bnr2, 10, SB_R2)
    GFOLD(bna1, 70, SB_A1) GFOLD(bnb1, 30, SB_B1) GFOLD(bnc1, 1, SB_C1)
    GFOLD(bna2, 70, SB_A2) GFOLD(bnb2, 30, SB_B2) GFOLD(bnc2, 1, SB_C2)
    return;
  }

  const float* src; int n; int mode; int rofs; float* dst = ws;
  int ofs = 0;
  int part = 0, nparts = 1;
  switch (b) {
    case 0:  src = w1;  ofs = WQ1;      n = 65;   mode = 0; rofs = 0;  break;
    case 1:  src = w2;  ofs = WQ2;      n = 450;  mode = 0; rofs = 0;  break;
    case 2:  src = wr1; ofs = WR1Q;     n = 100;  mode = 0; rofs = 0;  break;
    case 3:  src = wr2; ofs = WR2Q;     n = 100;  mode = 0; rofs = 0;  break;
    case 4:  src = wa1; ofs = WQAT;     n = 9800; mode = 1; rofs = 0;
             part = 0; nparts = 4; break;
    case 5:  src = wb1; ofs = WQBT;     n = 2100; mode = 2; rofs = 0;  break;
    case 6:  src = wc1; ofs = WCQ;      n = 30;   mode = 0; rofs = 0;  break;
    case 7:  src = wa2; ofs = WQAT;     n = 9800; mode = 1; rofs = 70;
             part = 0; nparts = 4; break;
    case 8:  src = wb2; ofs = WQBT;     n = 2100; mode = 2; rofs = 30; break;
    case 9:  src = wc2; ofs = WCQ + 32; n = 30;   mode = 0; rofs = 0;  break;
    case 11: case 12: case 13:
             src = wa1; ofs = WQAT;     n = 9800; mode = 1; rofs = 0;
             part = b - 10; nparts = 4; break;
    default: // 14,15,16
             src = wa2; ofs = WQAT;     n = 9800; mode = 1; rofs = 70;
             part = b - 13; nparts = 4; break;
  }

  const int n4 = n >> 2;
  const float4* s4 = (const float4*)src;

  float m = 0.f;
  for (int i = tid; i < n4; i += 256) {
    float4 v = s4[i];
    m = fmaxf(m, fmaxf(fmaxf(fabsf(v.x), fabsf(v.y)),
                       fmaxf(fabsf(v.z), fabsf(v.w))));
  }
  for (int i = (n4 << 2) + tid; i < n; i += 256) m = fmaxf(m, fabsf(src[i]));
#pragma unroll
  for (int off = 32; off > 0; off >>= 1)
    m = fmaxf(m, __shfl_down(m, off, 64));
  if ((tid & 63) == 0) s_red[tid >> 6] = m;
  __syncthreads();
  m = fmaxf(fmaxf(s_red[0], s_red[1]), fmaxf(s_red[2], s_red[3]));

  const float s = m / 127.0f;
  auto qz = [&](float w) {
    return rintf(fminf(fmaxf(w / s, -127.f), 127.f)) * s;
  };

  if (mode == 0) {
    for (int i = tid; i < n4; i += 256) {
      float4 v = s4[i];
      int base = 4 * i;
      dst[ofs + base]     = qz(v.x);
      dst[ofs + base + 1] = qz(v.y);
      dst[ofs + base + 2] = qz(v.z);
      dst[ofs + base + 3] = qz(v.w);
    }
    for (int i = (n4 << 2) + tid; i < n; i += 256) dst[ofs + i] = qz(src[i]);
  } else if (mode == 1) {           // A: row r, col c -> [c/4][r] float4
    // 140 % 4 == 0 => a float4 load never crosses a row; c % 4 == 0.
    // R21: this block quantizes only its quarter [lo, hi).
    const int chunk = (n4 + nparts - 1) / nparts;    // 613 for n4=2450
    const int lo = part * chunk;
    const int hi = (lo + chunk < n4) ? lo + chunk : n4;
    for (int i = lo + tid; i < hi; i += 256) {
      float4 v = s4[i];
      int base = 4 * i;
      int r = base / 140 + rofs, c = base % 140;
      float4 q4;
      q4.x = qz(v.x); q4.y = qz(v.y); q4.z = qz(v.z); q4.w = qz(v.w);
      *(float4*)&dst[ofs + ((c >> 2) * 140 + r) * 4] = q4;
    }
  } else {                          // B: row r, col c -> [c/2][r] float2
    // rows of 70 can be crossed mid-float4; recompute (r,c) per component
    for (int i = tid; i < n4; i += 256) {
      float4 v = s4[i];
      int base = 4 * i;
      float q[4] = {qz(v.x), qz(v.y), qz(v.z), qz(v.w)};
#pragma unroll
      for (int cpt = 0; cpt < 4; ++cpt) {
        int ii = base + cpt;
        int r = ii / 70 + rofs, c = ii % 70;
        dst[ofs + ((c >> 1) * 60 + r) * 2 + (c & 1)] = q[cpt];
      }
    }
  }
}

// -------- main pipeline: wave owns 2 elements, ZERO barriers --------------
// R21 taunet = R18 VERBATIM (session best, 131.4us). Five consecutive
// hypotheses (L1-BW wave-split, 2x occupancy, DS-read cut, VMEM weights,
// unroll 5) were all neutral-or-negative against this structure: taunet
// ~38us is a latency/issue mix at grid-capped 4 waves/SIMD that resists
// single-knob intervention. Do not touch.
extern "C" __global__ __launch_bounds__(TPB, 4)
void taunet(const float* __restrict__ x, const float* __restrict__ ws,
            float* __restrict__ out, int B)
{
  __shared__ __align__(16) float s_h1[EPB * H1S];   // pre1 out; later 140-vec
  __shared__ __align__(16) float s_e[EPB * ES];     // x -> h[140]|t30[60]
  __shared__ __align__(16) float s_small[SMALL_N];

  const int tid = threadIdx.x;
  const int g  = tid >> 5;    // element slot within block (half-wave)
  const int l  = tid & 31;    // lane within element (P1-P4, C)
  const int ln = tid & 63;    // lane within wave
  const int wv = tid >> 6;    // wave within block
  const int gp = 2 * wv;      // wave's first element slot
  const int elem = blockIdx.x * EPB + g;

  // per-wave redundant copy of small weights+BN (identical values -> benign
  // race; each wave's own writes are ordered before its reads => no barrier)
  {
    const float4* w4p = (const float4*)ws;
    for (int i = ln; i < (SMALL_N >> 2); i += 64)   // 313 float4 = 1252 floats
      *(float4*)&s_small[i * 4] = w4p[i];
    if (ln == 0) s_small[1252] = ws[1252];
  }

  // stage x: wave stages its own two elements (coalesced float4)
  {
    const float4* xb = (const float4*)x;
#pragma unroll
    for (int it = 0; it < 2; ++it) {
      int e = gp + it;
      int ge = blockIdx.x * EPB + e;
      if (ge < B) {
        float4 v = xb[ge * 64 + ln];
        *(float4*)&s_e[e * ES + ln * 4] = v;
      }
    }
  }

  const float* sb = &s_small[WSB];

  // ---- P1: pre1 (Cin=1, K=13, stride 5) -> h1[5][49] ----
  // weights + BN wave-uniform from ws[] -> scalar s_loads (SMEM pipe)
  {
    const float* xe = &s_e[g * ES];
#pragma unroll
    for (int rep = 0; rep < 2; ++rep) {
      int p = l + 32 * rep;
      bool act = p < 49;
      int ps = act ? p : 0;
      float win[13];
#pragma unroll
      for (int k = 0; k < 13; ++k) win[k] = xe[5 * ps + k];
#pragma unroll
      for (int ci = 0; ci < 5; ++ci) {
        float a0 = 0.f, a1 = 0.f;
#pragma unroll
        for (int k = 0; k < 13; ++k) {
          float d = fabsf(win[k] - ws[WQ1 + ci * 13 + k]);
          if (k & 1) a1 += d; else a0 += d;
        }
        float v = fmaxf(fmaf(-(a0 + a1), ws[WSB + SB_P1 + ci],
                             ws[WSB + SB_P1 + 5 + ci]), 0.f);
        if (act) s_h1[g * H1S + ci * 49 + ps] = v;
      }
    }
  }

  // ---- P2: pre2 (Cin=5, K=9, stride 3) -> h2[10][14] ----
  // half-wave: lane = ow(14 of 16) x co-half(2); ci-outer, 9-reg window
  {
    const int ch = l >> 4;
    const int ow16 = l & 15;
    const bool act = ow16 < 14;
    const int ow = act ? ow16 : 0;
    const float* h1b = &s_h1[g * H1S];
    float acc[5] = {0.f, 0.f, 0.f, 0.f, 0.f};
#pragma unroll
    for (int ci = 0; ci < 5; ++ci) {
      float w9[9];
#pragma unroll
      for (int k = 0; k < 9; ++k) w9[k] = h1b[ci * 49 + 3 * ow + k];
#pragma unroll
      for (int c = 0; c < 5; ++c) {
        int co = ch * 5 + c;
        float s0 = 0.f, s1 = 0.f;
#pragma unroll
        for (int k = 0; k < 9; ++k) {
          float d = fabsf(w9[k] - s_small[WQ2 + co * 45 + ci * 9 + k]);
          if (k & 1) s1 += d; else s0 += d;
        }
        acc[c] += s0 + s1;
      }
    }
#pragma unroll
    for (int c = 0; c < 5; ++c) {
      int co = ch * 5 + c;
      float v = fmaxf(fmaf(-acc[c], sb[SB_P2 + co], sb[SB_P2 + 10 + co]), 0.f);
      if (act) s_e[g * ES + co * 14 + ow] = v;
    }
  }

  // ---- P3: r1 (10x10, K=1) + relu -> t1 ----
#pragma unroll
  for (int j = 0; j < 5; ++j) {
    int idx = l + 32 * j;
    if (idx < 140) {
      int co = idx / 14, ow = idx % 14;
      float a0 = 0.f, a1 = 0.f;
#pragma unroll
      for (int ci = 0; ci < 10; ++ci) {
        float d = fabsf(s_e[g * ES + ci * 14 + ow] - s_small[WR1Q + co * 10 + ci]);
        if (ci & 1) a1 += d; else a0 += d;
      }
      s_e[g * ES + 140 + idx] =
          fmaxf(fmaf(-(a0 + a1), sb[SB_R1 + co], sb[SB_R1 + 10 + co]), 0.f);
    }
  }

  // ---- P4: r2 (no relu) + residual, h = relu(t2 + h2), in place ----
#pragma unroll
  for (int j = 0; j < 5; ++j) {
    int idx = l + 32 * j;
    if (idx < 140) {
      int co = idx / 14, ow = idx % 14;
      float a0 = 0.f, a1 = 0.f;
#pragma unroll
      for (int ci = 0; ci < 10; ++ci) {
        float d = fabsf(s_e[g * ES + 140 + ci * 14 + ow] - s_small[WR2Q + co * 10 + ci]);
        if (ci & 1) a1 += d; else a0 += d;
      }
      float t2 = fmaf(-(a0 + a1), sb[SB_R2 + co], sb[SB_R2 + 10 + co]);
      s_e[g * ES + idx] = fmaxf(t2 + s_e[g * ES + idx], 0.f);
    }
  }

  // ---- A/B fused branches, wave-wide ----
  {
    const float* hb0 = &s_e[gp * ES];         // element e0 = gp
    const float* hb1 = &s_e[(gp + 1) * ES];   // element e1 = gp+1

    // A: cb-outer; h4/k4 LDS-read ONCE per cb. Sets 0,1: rows ln / ln+64 for
    // BOTH elements (dual accumulators). Set 2 packed: rows 128-139 of elem0
    // on lanes 0-11, of elem1 on lanes 12-23 -> single-elem cost. p4 comes
    // from REGISTERS (cndmask h4/k4), not a 3rd LDS read (R18).
    const int r01[2] = {ln, ln + 64};
    const bool s2a = ln < 12;
    const bool s2b = (ln >= 12) && (ln < 24);
    const int r2 = 128 + (s2a ? ln : (s2b ? ln - 12 : 0));

    float accA[2][4], accB[2][4], acc2[4];
#pragma unroll
    for (int p = 0; p < 2; ++p)
#pragma unroll
      for (int j = 0; j < 4; ++j) { accA[p][j] = 0.f; accB[p][j] = 0.f; }
#pragma unroll
    for (int j = 0; j < 4; ++j) acc2[j] = 0.f;

#pragma unroll 2
    for (int cb = 0; cb < 35; ++cb) {
      float4 h4 = *(const float4*)&hb0[cb * 4];
      float4 k4 = *(const float4*)&hb1[cb * 4];
      float4 p4;                     // duplicate of h4 (lanes<12) / k4 (12..23)
      p4.x = s2a ? h4.x : k4.x;
      p4.y = s2a ? h4.y : k4.y;
      p4.z = s2a ? h4.z : k4.z;
      p4.w = s2a ? h4.w : k4.w;
#pragma unroll
      for (int p = 0; p < 2; ++p) {
        float4 w4 = *(const float4*)&ws[WQAT + (cb * 140 + r01[p]) * 4];
        accA[p][0] += fabsf(h4.x - w4.x);
        accA[p][1] += fabsf(h4.y - w4.y);
        accA[p][2] += fabsf(h4.z - w4.z);
        accA[p][3] += fabsf(h4.w - w4.w);
        accB[p][0] += fabsf(k4.x - w4.x);
        accB[p][1] += fabsf(k4.y - w4.y);
        accB[p][2] += fabsf(k4.z - w4.z);
        accB[p][3] += fabsf(k4.w - w4.w);
      }
      float4 w2v = *(const float4*)&ws[WQAT + (cb * 140 + r2) * 4];
      acc2[0] += fabsf(p4.x - w2v.x);
      acc2[1] += fabsf(p4.y - w2v.y);
      acc2[2] += fabsf(p4.z - w2v.z);
      acc2[3] += fabsf(p4.w - w2v.w);
    }
#pragma unroll
    for (int p = 0; p < 2; ++p) {
      int cl = r01[p];
      int co  = cl < 70 ? cl : cl - 70;
      int off = cl < 70 ? SB_A1 : SB_A2;
      float sc = sb[off + co], bi = sb[off + 70 + co];
      float sadA = (accA[p][0] + accA[p][1]) + (accA[p][2] + accA[p][3]);
      float sadB = (accB[p][0] + accB[p][1]) + (accB[p][2] + accB[p][3]);
      s_h1[gp * H1S + cl]       = fmaxf(fmaf(-sadA, sc, bi), 0.f);
      s_h1[(gp + 1) * H1S + cl] = fmaxf(fmaf(-sadB, sc, bi), 0.f);
    }
    if (s2a || s2b) {
      int cl = r2;                         // 128..139 -> always branch 2
      int co = cl - 70;
      float sc = sb[SB_A2 + co], bi = sb[SB_A2 + 70 + co];
      float sad = (acc2[0] + acc2[1]) + (acc2[2] + acc2[3]);
      int e = s2a ? gp : (gp + 1);
      s_h1[e * H1S + cl] = fmaxf(fmaf(-sad, sc, bi), 0.f);
    }

    // B: 60 fused rows in one pass; dense float2 weight loads + float2 h reads
    {
      bool act = ln < 60;
      int rl = act ? ln : 0;
      int br = rl >= 30;
      int co = br ? rl - 30 : rl;
      const float* h0 = &s_h1[gp * H1S + br * 70];
      const float* h1 = &s_h1[(gp + 1) * H1S + br * 70];
      int off = br ? SB_B2 : SB_B1;
      float a0 = 0.f, a1 = 0.f, b0 = 0.f, b1 = 0.f;
#pragma unroll 8
      for (int ci = 0; ci < 35; ++ci) {
        float2 w2v = *(const float2*)&ws[WQBT + (ci * 60 + rl) * 2];
        float2 hv0 = *(const float2*)&h0[2 * ci];
        float2 hv1 = *(const float2*)&h1[2 * ci];
        a0 += fabsf(hv0.x - w2v.x);
        a1 += fabsf(hv0.y - w2v.y);
        b0 += fabsf(hv1.x - w2v.x);
        b1 += fabsf(hv1.y - w2v.y);
      }
      if (act) {
        float sc = sb[off + co], bi = sb[off + 30 + co];
        s_e[gp * ES + 140 + rl]       = fmaxf(fmaf(-(a0 + a1), sc, bi), 0.f);
        s_e[(gp + 1) * ES + 140 + rl] = fmaxf(fmaf(-(b0 + b1), sc, bi), 0.f);
      }
    }

    // C: per element (half-wave), both branches sequentially; width-32 tree
    for (int br = 0; br < 2; ++br) {
      float d = 0.f;
      if (l < 30)
        d = fabsf(s_e[g * ES + 140 + br * 30 + l] - s_small[WCQ + br * 32 + l]);
#pragma unroll
      for (int off = 16; off > 0; off >>= 1)
        d += __shfl_down(d, off, 32);
      if (l == 0 && elem < B) {
        int sbC = br ? SB_C2 : SB_C1;
        out[br * B + elem] = fmaxf(fmaf(-d, sb[sbC], sb[sbC + 1]), 0.f);
      }
    }
  }
}

extern "C" void kernel_launch(void* const* d_in, const int* in_sizes, int n_in,
                              void* d_out, int out_size, void* d_ws, size_t ws_size,
                              hipStream_t stream) {
  const float* x    = (const float*)d_in[0];
  const float* w1   = (const float*)d_in[1];
  const float* bnp1 = (const float*)d_in[2];
  const float* w2   = (const float*)d_in[3];
  const float* bnp2 = (const float*)d_in[4];
  const float* wr1  = (const float*)d_in[5];
  const float* bnr1 = (const float*)d_in[6];
  const float* wr2  = (const float*)d_in[7];
  const float* bnr2 = (const float*)d_in[8];
  const float* wa1  = (const float*)d_in[9];
  const float* bna1 = (const float*)d_in[10];
  const float* wb1  = (const float*)d_in[11];
  const float* bnb1 = (const float*)d_in[12];
  const float* wc1  = (const float*)d_in[13];
  const float* bnc1 = (const float*)d_in[14];
  const float* wa2  = (const float*)d_in[15];
  const float* bna2 = (const float*)d_in[16];
  const float* wb2  = (const float*)d_in[17];
  const float* bnb2 = (const float*)d_in[18];
  const float* wc2  = (const float*)d_in[19];
  const float* bnc2 = (const float*)d_in[20];

  float* ws = (float*)d_ws;
  int B = in_sizes[0] / 256;
  int blocks = (B + EPB - 1) / EPB;

  hipLaunchKernelGGL(prep, dim3(17), dim3(256), 0, stream,
                     w1, bnp1, w2, bnp2, wr1, bnr1, wr2, bnr2,
                     wa1, bna1, wb1, bnb1, wc1, bnc1,
                     wa2, bna2, wb2, bnb2, wc2, bnc2, ws);

  hipLaunchKernelGGL(taunet, dim3(blocks), dim3(TPB), 0, stream,
                     x, ws, (float*)d_out, B);
}